// Round 8
// baseline (229.792 us; speedup 1.0000x reference)
//
#include <hip/hip_runtime.h>
#include <hip/hip_bf16.h>

// B=2, N=1024/branch, H=1024, NH=16, d=64, S=2N=2048. I/O f32; compute bf16 MFMA.
#define NB      2
#define NSEQ    1024
#define S2      2048
#define HDIM    1024
#define NHEADS  16
#define DHEAD   64
// Q is pre-scaled by 0.125*log2(e) in the QKV epilogue; attention uses exp2.
#define Q_SCALE 0.18033688011112042f

typedef unsigned short ushort_t;
typedef __attribute__((ext_vector_type(8))) short short8;   // 8 bf16 = 4 VGPR (MFMA A/B frag)
typedef __attribute__((ext_vector_type(4))) float f32x4;    // MFMA C/D frag

__device__ __forceinline__ ushort_t f2bf(float f) {
    union { float f; unsigned int u; } c; c.f = f;
    unsigned int u = c.u;
    u += 0x7FFFu + ((u >> 16) & 1u);   // RTNE
    return (ushort_t)(u >> 16);
}

__device__ __forceinline__ unsigned pack_bf16x2(float a, float b) {
    union { __hip_bfloat162 h; unsigned u; } cv;
    cv.h = __float22bfloat162_rn(float2{a, b});   // v_cvt_pk_bf16_f32 on gfx950
    return cv.u;
}

// ---------------------------------------------------------------------------
// One-shot f32 -> bf16 convert of x, x2, w_qkv, w_out into workspace.
// ---------------------------------------------------------------------------
__global__ __launch_bounds__(256) void cvt_all(
    const float* __restrict__ x, const float* __restrict__ x2,
    const float* __restrict__ wqkv, const float* __restrict__ wout,
    ushort_t* __restrict__ Xb, ushort_t* __restrict__ Wqb, ushort_t* __restrict__ Wob)
{
    int b = blockIdx.x;
    const float* s; ushort_t* d; int i;
    if (b < 2048)      { s = x;    d = Xb;            i = b * 256 + threadIdx.x; }
    else if (b < 4096) { s = x2;   d = Xb + 2097152;  i = (b - 2048) * 256 + threadIdx.x; }
    else if (b < 7168) { s = wqkv; d = Wqb;           i = (b - 4096) * 256 + threadIdx.x; }
    else               { s = wout; d = Wob;           i = (b - 7168) * 256 + threadIdx.x; }
    float4 v = ((const float4*)s)[i];
    ushort4 o; o.x = f2bf(v.x); o.y = f2bf(v.y); o.z = f2bf(v.z); o.w = f2bf(v.w);
    ((ushort4*)d)[i] = o;
}

// ---------------------------------------------------------------------------
// QKV MFMA GEMM: C[4096,3072] = Xb @ Wqb^T. 128x128 tile, BK=32,
// global_load_lds width 16, XOR-swizzled LDS. Epilogue: Q (scaled), K ->
// [b,h,s,d] via per-wave LDS transpose -> packed 8B stores; V -> [b,h,d,s]
// direct ushort4 (already 32B-segment coalesced).
// ---------------------------------------------------------------------------
__global__ __launch_bounds__(256) void qkv_gemm_mfma(
    const ushort_t* __restrict__ Xb, const ushort_t* __restrict__ Wqb,
    ushort_t* __restrict__ Qb, ushort_t* __restrict__ Kb, ushort_t* __restrict__ Vtb)
{
    __shared__ ushort_t As[128 * 32];
    __shared__ ushort_t Bs[128 * 32];
    __shared__ float    Sc[4][16 * 20];   // per-wave epilogue scratch, pitch 20 (<=2-way banks)
    const int t = threadIdx.x;
    const int lane = t & 63, quad = lane >> 4, l15 = lane & 15;
    const int w = t >> 6;
    const int wm = (w >> 1) * 64, wn = (w & 1) * 64;
    const int r0 = blockIdx.y * 128, c0 = blockIdx.x * 128;

    const int g_chunk = (lane & 3) ^ ((lane >> 3) & 3);   // lane-const global chunk
    const int srow_lo = w * 16 + (lane >> 2);             // row for issue p=0 (p adds 64)

    f32x4 acc[4][4];
    #pragma unroll
    for (int i = 0; i < 4; ++i)
        #pragma unroll
        for (int j = 0; j < 4; ++j) acc[i][j] = (f32x4){0.f, 0.f, 0.f, 0.f};

    for (int k0 = 0; k0 < HDIM; k0 += 32) {
        __syncthreads();
        #pragma unroll
        for (int p = 0; p < 2; ++p) {
            int row = srow_lo + p * 64;
            const ushort_t* gpA = Xb  + (size_t)(r0 + row) * HDIM + k0 + g_chunk * 8;
            const ushort_t* gpB = Wqb + (size_t)(c0 + row) * HDIM + k0 + g_chunk * 8;
            ushort_t* lpA = As + p * 2048 + w * 512;   // wave-uniform base; +lane*16B implicit
            ushort_t* lpB = Bs + p * 2048 + w * 512;
            __builtin_amdgcn_global_load_lds(
                (const __attribute__((address_space(1))) void*)gpA,
                (__attribute__((address_space(3))) void*)lpA, 16, 0, 0);
            __builtin_amdgcn_global_load_lds(
                (const __attribute__((address_space(1))) void*)gpB,
                (__attribute__((address_space(3))) void*)lpB, 16, 0, 0);
        }
        __syncthreads();
        const int sw = (l15 >> 1) & 3;   // (ra>>1)&3 for frag rows
        short8 af[4], bf[4];
        #pragma unroll
        for (int mi = 0; mi < 4; ++mi) {
            int ra = wm + mi * 16 + l15;
            af[mi] = *(const short8*)(As + ra * 32 + ((quad ^ sw) * 8));
        }
        #pragma unroll
        for (int ni = 0; ni < 4; ++ni) {
            int rb = wn + ni * 16 + l15;
            bf[ni] = *(const short8*)(Bs + rb * 32 + ((quad ^ sw) * 8));
        }
        #pragma unroll
        for (int mi = 0; mi < 4; ++mi)
            #pragma unroll
            for (int ni = 0; ni < 4; ++ni)
                acc[mi][ni] = __builtin_amdgcn_mfma_f32_16x16x32_bf16(af[mi], bf[ni], acc[mi][ni], 0, 0, 0);
    }

    const int branch = r0 >> 11;
    const int bb     = (r0 & 2047) >> 10;
    const int qi     = c0 >> 10;            // 0=Q 1=K 2=V
    float* sc = &Sc[w][0];

    if (qi == 2) {
        // V path: transposed ushort4 stores (16 rows x 32B per inst) — unchanged
        #pragma unroll
        for (int mi = 0; mi < 4; ++mi) {
            int sbase = branch * NSEQ + (r0 & 1023) + wm + mi * 16 + quad * 4;
            #pragma unroll
            for (int ni = 0; ni < 4; ++ni) {
                int cc = (c0 & 1023) + wn + ni * 16;
                int h  = cc >> 6;
                int dd = (cc & 63) + l15;
                ushort4 pv;
                pv.x = f2bf(acc[mi][ni][0]); pv.y = f2bf(acc[mi][ni][1]);
                pv.z = f2bf(acc[mi][ni][2]); pv.w = f2bf(acc[mi][ni][3]);
                *(ushort4*)(Vtb + ((size_t)(bb * NHEADS + h) * DHEAD + dd) * S2 + sbase) = pv;
            }
        }
    } else {
        // Q/K path: LDS transpose -> one packed 8B store per 16x16 tile
        const float qsc = (qi == 0) ? Q_SCALE : 1.0f;
        ushort_t* base = (qi ? Kb : Qb);
        const int row = lane >> 2, ch = lane & 3;
        #pragma unroll
        for (int mi = 0; mi < 4; ++mi) {
            int sb = branch * NSEQ + (r0 & 1023) + wm + mi * 16;   // 16-row s base
            #pragma unroll
            for (int ni = 0; ni < 4; ++ni) {
                int cc = (c0 & 1023) + wn + ni * 16;
                int h  = cc >> 6;
                int db = cc & 63;          // 16-wide d base
                #pragma unroll
                for (int reg = 0; reg < 4; ++reg)
                    sc[(quad * 4 + reg) * 20 + l15] = acc[mi][ni][reg] * qsc;
                float4 v = *(const float4*)&sc[row * 20 + ch * 4];
                uint2 pk;
                pk.x = pack_bf16x2(v.x, v.y);
                pk.y = pack_bf16x2(v.z, v.w);
                *(uint2*)(base + ((size_t)(bb * NHEADS + h) * S2 + sb + row) * DHEAD + db + ch * 4) = pk;
            }
        }
    }
}

// ---------------------------------------------------------------------------
// MFMA flash attention v5 per (b,h). Block = 128 q-rows, 4 waves x 32 rows
// (two 16-row sets per wave). K/V async-staged (global_load_lds dbuf,
// 1 barrier/tile, prefetch after barrier). NO-MAX softmax. K/V fragments
// loaded once per tile, reused across both q-sets.
// ---------------------------------------------------------------------------
__global__ __launch_bounds__(256) void attn_mfma(
    const ushort_t* __restrict__ Qb, const ushort_t* __restrict__ Kb,
    const ushort_t* __restrict__ Vtb, ushort_t* __restrict__ Ob)
{
    __shared__ ushort_t Ks[2][64 * 64];   // 8 KB/buf, 128 B rows, chunk-swizzled
    __shared__ ushort_t Vs[2][64 * 64];   // rows = d-dims (from Vt)
    __shared__ ushort_t Ps[64][72];       // per-wave 16 rows, reused by both sets

    const int t = threadIdx.x, lane = t & 63, quad = lane >> 4, l15 = lane & 15, w = t >> 6;
    const int bh = blockIdx.z * NHEADS + blockIdx.y;
    const int r0 = blockIdx.x * 128;
    const ushort_t* Qh  = Qb  + (size_t)bh * S2 * DHEAD;
    const ushort_t* Kh  = Kb  + (size_t)bh * S2 * DHEAD;
    const ushort_t* Vth = Vtb + (size_t)bh * DHEAD * S2;

    const int slot = lane & 7;        // LDS slot chunk this lane fills
    const int rsub = lane >> 3;       // row-within-issue-group 0..7
    auto prefetch = [&](int kt_, int buf_) {
        #pragma unroll
        for (int c = 0; c < 2; ++c) {
            int row = w * 16 + c * 8 + rsub;
            int gK  = slot ^ ((row >> 2) & 7);   // K swizzle (matches key=4*l15+nt reads)
            int gV  = slot ^ (row & 7);          // V swizzle (matches drow=nt*16+l15 reads)
            const ushort_t* gpK = Kh  + (size_t)(kt_ * 64 + row) * DHEAD + gK * 8;
            const ushort_t* gpV = Vth + (size_t)row * S2 + kt_ * 64 + gV * 8;
            ushort_t* lpK = &Ks[buf_][w * 1024 + c * 512];
            ushort_t* lpV = &Vs[buf_][w * 1024 + c * 512];
            __builtin_amdgcn_global_load_lds(
                (const __attribute__((address_space(1))) void*)gpK,
                (__attribute__((address_space(3))) void*)lpK, 16, 0, 0);
            __builtin_amdgcn_global_load_lds(
                (const __attribute__((address_space(1))) void*)gpV,
                (__attribute__((address_space(3))) void*)lpV, 16, 0, 0);
        }
    };

    // Q fragments direct from global (once): two 16-row sets per wave
    short8 aq[2][2];
    #pragma unroll
    for (int s = 0; s < 2; ++s) {
        const int qrow = r0 + 32 * w + 16 * s + l15;
        aq[s][0] = *(const short8*)(Qh + (size_t)qrow * DHEAD + quad * 8);
        aq[s][1] = *(const short8*)(Qh + (size_t)qrow * DHEAD + 32 + quad * 8);
    }

    float lacc[2][4] = {};
    f32x4 oacc[2][4];
    #pragma unroll
    for (int s = 0; s < 2; ++s)
        #pragma unroll
        for (int nt = 0; nt < 4; ++nt) oacc[s][nt] = (f32x4){0.f, 0.f, 0.f, 0.f};

    prefetch(0, 0);
    prefetch(1, 1);
    __syncthreads();

    for (int kt = 0; kt < S2 / 64; ++kt) {
        const ushort_t* kb = &Ks[kt & 1][0];
        const ushort_t* vb = &Vs[kt & 1][0];

        // K fragments once per tile, reused for both q-sets
        short8 kf[4][2];
        #pragma unroll
        for (int nt = 0; nt < 4; ++nt) {
            const int key = 4 * l15 + nt;
            const ushort_t* krow = kb + key * 64;
            const int swz = l15 & 7;             // (key>>2)&7
            kf[nt][0] = *(const short8*)(krow + ((quad       ^ swz) * 8));
            kf[nt][1] = *(const short8*)(krow + (((4 + quad) ^ swz) * 8));
        }

        // QK^T for both sets
        f32x4 sacc[2][4];
        #pragma unroll
        for (int s = 0; s < 2; ++s)
            #pragma unroll
            for (int nt = 0; nt < 4; ++nt) {
                f32x4 sv = (f32x4){0.f, 0.f, 0.f, 0.f};
                sv = __builtin_amdgcn_mfma_f32_16x16x32_bf16(aq[s][0], kf[nt][0], sv, 0, 0, 0);
                sv = __builtin_amdgcn_mfma_f32_16x16x32_bf16(aq[s][1], kf[nt][1], sv, 0, 0, 0);
                sacc[s][nt] = sv;
            }

        // V fragments once per tile, reused for both PV sets
        short8 vf[4][2];
        #pragma unroll
        for (int nt = 0; nt < 4; ++nt) {
            const int drow = nt * 16 + l15;
            vf[nt][0] = *(const short8*)(vb + drow * 64 + ((quad       ^ (drow & 7)) * 8));
            vf[nt][1] = *(const short8*)(vb + drow * 64 + (((4 + quad) ^ (drow & 7)) * 8));
        }

        #pragma unroll
        for (int s = 0; s < 2; ++s) {
            // no-max softmax: p = exp2(score); packed P write (keys 4*l15..+3)
            #pragma unroll
            for (int reg = 0; reg < 4; ++reg) {
                float p0 = __builtin_exp2f(sacc[s][0][reg]);
                float p1 = __builtin_exp2f(sacc[s][1][reg]);
                float p2 = __builtin_exp2f(sacc[s][2][reg]);
                float p3 = __builtin_exp2f(sacc[s][3][reg]);
                lacc[s][reg] += (p0 + p1) + (p2 + p3);
                uint2 pk;
                pk.x = pack_bf16x2(p0, p1);
                pk.y = pack_bf16x2(p2, p3);
                int prow = 16 * w + quad * 4 + reg;
                *(uint2*)&Ps[prow][4 * l15] = pk;
            }
            // PV: A = P (same-wave LDS rows), B = V fragments (reused regs)
            #pragma unroll
            for (int kk = 0; kk < 2; ++kk) {
                short8 pa = *(const short8*)&Ps[16 * w + l15][kk * 32 + quad * 8];
                #pragma unroll
                for (int nt = 0; nt < 4; ++nt)
                    oacc[s][nt] = __builtin_amdgcn_mfma_f32_16x16x32_bf16(pa, vf[nt][kk], oacc[s][nt], 0, 0, 0);
            }
        }

        // one barrier per tile; then overwrite the buffer everyone just finished
        __syncthreads();
        if (kt + 2 < S2 / 64) prefetch(kt + 2, kt & 1);
    }

    // final l: reduce per-lane partials across the 16 lanes sharing each row
    #pragma unroll
    for (int s = 0; s < 2; ++s)
        #pragma unroll
        for (int reg = 0; reg < 4; ++reg) {
            float l = lacc[s][reg];
            l += __shfl_xor(l, 1);
            l += __shfl_xor(l, 2);
            l += __shfl_xor(l, 4);
            l += __shfl_xor(l, 8);
            float inv = 1.f / l;
            size_t rowoff = ((size_t)bh * S2 + r0 + 32 * w + 16 * s + quad * 4 + reg) * DHEAD;
            #pragma unroll
            for (int nt = 0; nt < 4; ++nt)
                Ob[rowoff + nt * 16 + l15] = f2bf(oacc[s][nt][reg] * inv);
        }
}

// ---------------------------------------------------------------------------
// Proj MFMA GEMM: out[4096,1024] (f32) = gather(O)[4096,1024] @ Wob^T + b_out.
// Epilogue via per-wave LDS transpose -> one 16B f32x4 store per 16x16 tile.
// ---------------------------------------------------------------------------
__global__ __launch_bounds__(256) void proj_gemm_mfma(
    const ushort_t* __restrict__ Ob, const ushort_t* __restrict__ Wob,
    const float* __restrict__ Bo, float* __restrict__ Out)
{
    __shared__ ushort_t As[128 * 32];
    __shared__ ushort_t Bs[128 * 32];
    __shared__ float    Sc[4][16 * 20];
    const int t = threadIdx.x;
    const int lane = t & 63, quad = lane >> 4, l15 = lane & 15;
    const int w = t >> 6;
    const int wm = (w >> 1) * 64, wn = (w & 1) * 64;
    const int r0 = blockIdx.y * 128, c0 = blockIdx.x * 128;
    const int branch = r0 >> 11, bb = (r0 & 2047) >> 10;

    const int g_chunk = (lane & 3) ^ ((lane >> 3) & 3);
    const int srow_lo = w * 16 + (lane >> 2);

    f32x4 acc[4][4];
    #pragma unroll
    for (int i = 0; i < 4; ++i)
        #pragma unroll
        for (int j = 0; j < 4; ++j) acc[i][j] = (f32x4){0.f, 0.f, 0.f, 0.f};

    for (int k0 = 0; k0 < HDIM; k0 += 32) {
        int h = k0 >> 6, off = k0 & 63;
        __syncthreads();
        #pragma unroll
        for (int p = 0; p < 2; ++p) {
            int row = srow_lo + p * 64;
            int s = branch * NSEQ + (r0 & 1023) + row;
            const ushort_t* gpA = Ob + ((size_t)(bb * NHEADS + h) * S2 + s) * DHEAD + off + g_chunk * 8;
            const ushort_t* gpB = Wob + (size_t)(c0 + row) * HDIM + k0 + g_chunk * 8;
            ushort_t* lpA = As + p * 2048 + w * 512;
            ushort_t* lpB = Bs + p * 2048 + w * 512;
            __builtin_amdgcn_global_load_lds(
                (const __attribute__((address_space(1))) void*)gpA,
                (__attribute__((address_space(3))) void*)lpA, 16, 0, 0);
            __builtin_amdgcn_global_load_lds(
                (const __attribute__((address_space(1))) void*)gpB,
                (__attribute__((address_space(3))) void*)lpB, 16, 0, 0);
        }
        __syncthreads();
        const int sw = (l15 >> 1) & 3;
        short8 af[4], bf[4];
        #pragma unroll
        for (int mi = 0; mi < 4; ++mi) {
            int ra = wm + mi * 16 + l15;
            af[mi] = *(const short8*)(As + ra * 32 + ((quad ^ sw) * 8));
        }
        #pragma unroll
        for (int ni = 0; ni < 4; ++ni) {
            int rb = wn + ni * 16 + l15;
            bf[ni] = *(const short8*)(Bs + rb * 32 + ((quad ^ sw) * 8));
        }
        #pragma unroll
        for (int mi = 0; mi < 4; ++mi)
            #pragma unroll
            for (int ni = 0; ni < 4; ++ni)
                acc[mi][ni] = __builtin_amdgcn_mfma_f32_16x16x32_bf16(af[mi], bf[ni], acc[mi][ni], 0, 0, 0);
    }

    float* sc = &Sc[w][0];
    const int row = lane >> 2, ch = lane & 3;
    #pragma unroll
    for (int mi = 0; mi < 4; ++mi) {
        int rb0 = r0 + wm + mi * 16;
        #pragma unroll
        for (int ni = 0; ni < 4; ++ni) {
            int cb = c0 + wn + ni * 16;
            #pragma unroll
            for (int reg = 0; reg < 4; ++reg)
                sc[(quad * 4 + reg) * 20 + l15] = acc[mi][ni][reg];
            float4 v = *(const float4*)&sc[row * 20 + ch * 4];
            float4 bias = *(const float4*)&Bo[cb + ch * 4];
            v.x += bias.x; v.y += bias.y; v.z += bias.z; v.w += bias.w;
            *(float4*)&Out[(size_t)(rb0 + row) * HDIM + cb + ch * 4] = v;
        }
    }
}

extern "C" void kernel_launch(void* const* d_in, const int* in_sizes, int n_in,
                              void* d_out, int out_size, void* d_ws, size_t ws_size,
                              hipStream_t stream) {
    const float* x    = (const float*)d_in[0];
    const float* x2   = (const float*)d_in[1];
    const float* wqkv = (const float*)d_in[2];
    const float* wout = (const float*)d_in[3];
    const float* bout = (const float*)d_in[4];
    float* out = (float*)d_out;

    // ws layout (bytes): Xb 8M | Wqb 6M | Wob 2M | Qb 8M | Kb 8M | Vtb 8M | Ob 8M = 48 MB
    char* ws = (char*)d_ws;
    ushort_t* Xb  = (ushort_t*)(ws);
    ushort_t* Wqb = (ushort_t*)(ws + (8u  << 20));
    ushort_t* Wob = (ushort_t*)(ws + (14u << 20));
    ushort_t* Qb  = (ushort_t*)(ws + (16u << 20));
    ushort_t* Kb  = (ushort_t*)(ws + (24u << 20));
    ushort_t* Vtb = (ushort_t*)(ws + (32u << 20));
    ushort_t* Ob  = (ushort_t*)(ws + (40u << 20));

    cvt_all<<<8192, 256, 0, stream>>>(x, x2, wqkv, wout, Xb, Wqb, Wob);
    qkv_gemm_mfma<<<dim3(24, 32), 256, 0, stream>>>(Xb, Wqb, Qb, Kb, Vtb);
    attn_mfma<<<dim3(S2 / 128, NHEADS, NB), 256, 0, stream>>>(Qb, Kb, Vtb, Ob);
    proj_gemm_mfma<<<dim3(8, 32), 256, 0, stream>>>(Ob, Wob, bout, out);
}

// Round 9
// 224.626 us; speedup vs baseline: 1.0230x; 1.0230x over previous
//
#include <hip/hip_runtime.h>
#include <hip/hip_bf16.h>

// B=2, N=1024/branch, H=1024, NH=16, d=64, S=2N=2048. I/O f32; compute bf16 MFMA.
#define NB      2
#define NSEQ    1024
#define S2      2048
#define HDIM    1024
#define NHEADS  16
#define DHEAD   64
// Q is pre-scaled by 0.125*log2(e) in the QKV epilogue; attention uses exp2.
#define Q_SCALE 0.18033688011112042f

typedef unsigned short ushort_t;
typedef __attribute__((ext_vector_type(8))) short short8;   // 8 bf16 = 4 VGPR (MFMA A/B frag)
typedef __attribute__((ext_vector_type(4))) float f32x4;    // MFMA C/D frag

__device__ __forceinline__ ushort_t f2bf(float f) {
    union { float f; unsigned int u; } c; c.f = f;
    unsigned int u = c.u;
    u += 0x7FFFu + ((u >> 16) & 1u);   // RTNE
    return (ushort_t)(u >> 16);
}

__device__ __forceinline__ unsigned pack_bf16x2(float a, float b) {
    union { __hip_bfloat162 h; unsigned u; } cv;
    cv.h = __float22bfloat162_rn(float2{a, b});   // v_cvt_pk_bf16_f32 on gfx950
    return cv.u;
}

// ---------------------------------------------------------------------------
// One-shot f32 -> bf16 convert of x, x2, w_qkv, w_out into workspace.
// ---------------------------------------------------------------------------
__global__ __launch_bounds__(256) void cvt_all(
    const float* __restrict__ x, const float* __restrict__ x2,
    const float* __restrict__ wqkv, const float* __restrict__ wout,
    ushort_t* __restrict__ Xb, ushort_t* __restrict__ Wqb, ushort_t* __restrict__ Wob)
{
    int b = blockIdx.x;
    const float* s; ushort_t* d; int i;
    if (b < 2048)      { s = x;    d = Xb;            i = b * 256 + threadIdx.x; }
    else if (b < 4096) { s = x2;   d = Xb + 2097152;  i = (b - 2048) * 256 + threadIdx.x; }
    else if (b < 7168) { s = wqkv; d = Wqb;           i = (b - 4096) * 256 + threadIdx.x; }
    else               { s = wout; d = Wob;           i = (b - 7168) * 256 + threadIdx.x; }
    float4 v = ((const float4*)s)[i];
    ushort4 o; o.x = f2bf(v.x); o.y = f2bf(v.y); o.z = f2bf(v.z); o.w = f2bf(v.w);
    ((ushort4*)d)[i] = o;
}

// ---------------------------------------------------------------------------
// QKV MFMA GEMM: C[4096,3072] = Xb @ Wqb^T. 128x128 tile, BK=32,
// global_load_lds width 16, XOR-swizzled LDS. Epilogue: Q (scaled), K ->
// [b,h,s,d] via per-wave LDS transpose -> packed 8B stores; V -> [b,h,d,s]
// direct ushort4.
// ---------------------------------------------------------------------------
__global__ __launch_bounds__(256) void qkv_gemm_mfma(
    const ushort_t* __restrict__ Xb, const ushort_t* __restrict__ Wqb,
    ushort_t* __restrict__ Qb, ushort_t* __restrict__ Kb, ushort_t* __restrict__ Vtb)
{
    __shared__ ushort_t As[128 * 32];
    __shared__ ushort_t Bs[128 * 32];
    __shared__ float    Sc[4][16 * 20];   // per-wave epilogue scratch, pitch 20 (<=2-way banks)
    const int t = threadIdx.x;
    const int lane = t & 63, quad = lane >> 4, l15 = lane & 15;
    const int w = t >> 6;
    const int wm = (w >> 1) * 64, wn = (w & 1) * 64;
    const int r0 = blockIdx.y * 128, c0 = blockIdx.x * 128;

    const int g_chunk = (lane & 3) ^ ((lane >> 3) & 3);   // lane-const global chunk
    const int srow_lo = w * 16 + (lane >> 2);             // row for issue p=0 (p adds 64)

    f32x4 acc[4][4];
    #pragma unroll
    for (int i = 0; i < 4; ++i)
        #pragma unroll
        for (int j = 0; j < 4; ++j) acc[i][j] = (f32x4){0.f, 0.f, 0.f, 0.f};

    for (int k0 = 0; k0 < HDIM; k0 += 32) {
        __syncthreads();
        #pragma unroll
        for (int p = 0; p < 2; ++p) {
            int row = srow_lo + p * 64;
            const ushort_t* gpA = Xb  + (size_t)(r0 + row) * HDIM + k0 + g_chunk * 8;
            const ushort_t* gpB = Wqb + (size_t)(c0 + row) * HDIM + k0 + g_chunk * 8;
            ushort_t* lpA = As + p * 2048 + w * 512;   // wave-uniform base; +lane*16B implicit
            ushort_t* lpB = Bs + p * 2048 + w * 512;
            __builtin_amdgcn_global_load_lds(
                (const __attribute__((address_space(1))) void*)gpA,
                (__attribute__((address_space(3))) void*)lpA, 16, 0, 0);
            __builtin_amdgcn_global_load_lds(
                (const __attribute__((address_space(1))) void*)gpB,
                (__attribute__((address_space(3))) void*)lpB, 16, 0, 0);
        }
        __syncthreads();
        const int sw = (l15 >> 1) & 3;   // (ra>>1)&3 for frag rows
        short8 af[4], bf[4];
        #pragma unroll
        for (int mi = 0; mi < 4; ++mi) {
            int ra = wm + mi * 16 + l15;
            af[mi] = *(const short8*)(As + ra * 32 + ((quad ^ sw) * 8));
        }
        #pragma unroll
        for (int ni = 0; ni < 4; ++ni) {
            int rb = wn + ni * 16 + l15;
            bf[ni] = *(const short8*)(Bs + rb * 32 + ((quad ^ sw) * 8));
        }
        #pragma unroll
        for (int mi = 0; mi < 4; ++mi)
            #pragma unroll
            for (int ni = 0; ni < 4; ++ni)
                acc[mi][ni] = __builtin_amdgcn_mfma_f32_16x16x32_bf16(af[mi], bf[ni], acc[mi][ni], 0, 0, 0);
    }

    const int branch = r0 >> 11;
    const int bb     = (r0 & 2047) >> 10;
    const int qi     = c0 >> 10;            // 0=Q 1=K 2=V
    float* sc = &Sc[w][0];

    if (qi == 2) {
        #pragma unroll
        for (int mi = 0; mi < 4; ++mi) {
            int sbase = branch * NSEQ + (r0 & 1023) + wm + mi * 16 + quad * 4;
            #pragma unroll
            for (int ni = 0; ni < 4; ++ni) {
                int cc = (c0 & 1023) + wn + ni * 16;
                int h  = cc >> 6;
                int dd = (cc & 63) + l15;
                ushort4 pv;
                pv.x = f2bf(acc[mi][ni][0]); pv.y = f2bf(acc[mi][ni][1]);
                pv.z = f2bf(acc[mi][ni][2]); pv.w = f2bf(acc[mi][ni][3]);
                *(ushort4*)(Vtb + ((size_t)(bb * NHEADS + h) * DHEAD + dd) * S2 + sbase) = pv;
            }
        }
    } else {
        const float qsc = (qi == 0) ? Q_SCALE : 1.0f;
        ushort_t* base = (qi ? Kb : Qb);
        const int row = lane >> 2, ch = lane & 3;
        #pragma unroll
        for (int mi = 0; mi < 4; ++mi) {
            int sb = branch * NSEQ + (r0 & 1023) + wm + mi * 16;
            #pragma unroll
            for (int ni = 0; ni < 4; ++ni) {
                int cc = (c0 & 1023) + wn + ni * 16;
                int h  = cc >> 6;
                int db = cc & 63;
                #pragma unroll
                for (int reg = 0; reg < 4; ++reg)
                    sc[(quad * 4 + reg) * 20 + l15] = acc[mi][ni][reg] * qsc;
                float4 v = *(const float4*)&sc[row * 20 + ch * 4];
                uint2 pk;
                pk.x = pack_bf16x2(v.x, v.y);
                pk.y = pack_bf16x2(v.z, v.w);
                *(uint2*)(base + ((size_t)(bb * NHEADS + h) * S2 + sb + row) * DHEAD + db + ch * 4) = pk;
            }
        }
    }
}

// ---------------------------------------------------------------------------
// MFMA flash attention v5 per (b,h). Block = 128 q-rows, 4 waves x 32 rows
// (two 16-row sets per wave). K/V async-staged (global_load_lds dbuf,
// 1 barrier/tile, prefetch after barrier). NO-MAX softmax. K/V fragments
// loaded once per tile, reused across both q-sets.
// ---------------------------------------------------------------------------
__global__ __launch_bounds__(256) void attn_mfma(
    const ushort_t* __restrict__ Qb, const ushort_t* __restrict__ Kb,
    const ushort_t* __restrict__ Vtb, ushort_t* __restrict__ Ob)
{
    __shared__ ushort_t Ks[2][64 * 64];
    __shared__ ushort_t Vs[2][64 * 64];
    __shared__ ushort_t Ps[64][72];

    const int t = threadIdx.x, lane = t & 63, quad = lane >> 4, l15 = lane & 15, w = t >> 6;
    const int bh = blockIdx.z * NHEADS + blockIdx.y;
    const int r0 = blockIdx.x * 128;
    const ushort_t* Qh  = Qb  + (size_t)bh * S2 * DHEAD;
    const ushort_t* Kh  = Kb  + (size_t)bh * S2 * DHEAD;
    const ushort_t* Vth = Vtb + (size_t)bh * DHEAD * S2;

    const int slot = lane & 7;
    const int rsub = lane >> 3;
    auto prefetch = [&](int kt_, int buf_) {
        #pragma unroll
        for (int c = 0; c < 2; ++c) {
            int row = w * 16 + c * 8 + rsub;
            int gK  = slot ^ ((row >> 2) & 7);
            int gV  = slot ^ (row & 7);
            const ushort_t* gpK = Kh  + (size_t)(kt_ * 64 + row) * DHEAD + gK * 8;
            const ushort_t* gpV = Vth + (size_t)row * S2 + kt_ * 64 + gV * 8;
            ushort_t* lpK = &Ks[buf_][w * 1024 + c * 512];
            ushort_t* lpV = &Vs[buf_][w * 1024 + c * 512];
            __builtin_amdgcn_global_load_lds(
                (const __attribute__((address_space(1))) void*)gpK,
                (__attribute__((address_space(3))) void*)lpK, 16, 0, 0);
            __builtin_amdgcn_global_load_lds(
                (const __attribute__((address_space(1))) void*)gpV,
                (__attribute__((address_space(3))) void*)lpV, 16, 0, 0);
        }
    };

    short8 aq[2][2];
    #pragma unroll
    for (int s = 0; s < 2; ++s) {
        const int qrow = r0 + 32 * w + 16 * s + l15;
        aq[s][0] = *(const short8*)(Qh + (size_t)qrow * DHEAD + quad * 8);
        aq[s][1] = *(const short8*)(Qh + (size_t)qrow * DHEAD + 32 + quad * 8);
    }

    float lacc[2][4] = {};
    f32x4 oacc[2][4];
    #pragma unroll
    for (int s = 0; s < 2; ++s)
        #pragma unroll
        for (int nt = 0; nt < 4; ++nt) oacc[s][nt] = (f32x4){0.f, 0.f, 0.f, 0.f};

    prefetch(0, 0);
    prefetch(1, 1);
    __syncthreads();

    for (int kt = 0; kt < S2 / 64; ++kt) {
        const ushort_t* kb = &Ks[kt & 1][0];
        const ushort_t* vb = &Vs[kt & 1][0];

        short8 kf[4][2];
        #pragma unroll
        for (int nt = 0; nt < 4; ++nt) {
            const int key = 4 * l15 + nt;
            const ushort_t* krow = kb + key * 64;
            const int swz = l15 & 7;
            kf[nt][0] = *(const short8*)(krow + ((quad       ^ swz) * 8));
            kf[nt][1] = *(const short8*)(krow + (((4 + quad) ^ swz) * 8));
        }

        f32x4 sacc[2][4];
        #pragma unroll
        for (int s = 0; s < 2; ++s)
            #pragma unroll
            for (int nt = 0; nt < 4; ++nt) {
                f32x4 sv = (f32x4){0.f, 0.f, 0.f, 0.f};
                sv = __builtin_amdgcn_mfma_f32_16x16x32_bf16(aq[s][0], kf[nt][0], sv, 0, 0, 0);
                sv = __builtin_amdgcn_mfma_f32_16x16x32_bf16(aq[s][1], kf[nt][1], sv, 0, 0, 0);
                sacc[s][nt] = sv;
            }

        short8 vf[4][2];
        #pragma unroll
        for (int nt = 0; nt < 4; ++nt) {
            const int drow = nt * 16 + l15;
            vf[nt][0] = *(const short8*)(vb + drow * 64 + ((quad       ^ (drow & 7)) * 8));
            vf[nt][1] = *(const short8*)(vb + drow * 64 + (((4 + quad) ^ (drow & 7)) * 8));
        }

        #pragma unroll
        for (int s = 0; s < 2; ++s) {
            #pragma unroll
            for (int reg = 0; reg < 4; ++reg) {
                float p0 = __builtin_exp2f(sacc[s][0][reg]);
                float p1 = __builtin_exp2f(sacc[s][1][reg]);
                float p2 = __builtin_exp2f(sacc[s][2][reg]);
                float p3 = __builtin_exp2f(sacc[s][3][reg]);
                lacc[s][reg] += (p0 + p1) + (p2 + p3);
                uint2 pk;
                pk.x = pack_bf16x2(p0, p1);
                pk.y = pack_bf16x2(p2, p3);
                int prow = 16 * w + quad * 4 + reg;
                *(uint2*)&Ps[prow][4 * l15] = pk;
            }
            #pragma unroll
            for (int kk = 0; kk < 2; ++kk) {
                short8 pa = *(const short8*)&Ps[16 * w + l15][kk * 32 + quad * 8];
                #pragma unroll
                for (int nt = 0; nt < 4; ++nt)
                    oacc[s][nt] = __builtin_amdgcn_mfma_f32_16x16x32_bf16(pa, vf[nt][kk], oacc[s][nt], 0, 0, 0);
            }
        }

        __syncthreads();
        if (kt + 2 < S2 / 64) prefetch(kt + 2, kt & 1);
    }

    #pragma unroll
    for (int s = 0; s < 2; ++s)
        #pragma unroll
        for (int reg = 0; reg < 4; ++reg) {
            float l = lacc[s][reg];
            l += __shfl_xor(l, 1);
            l += __shfl_xor(l, 2);
            l += __shfl_xor(l, 4);
            l += __shfl_xor(l, 8);
            float inv = 1.f / l;
            size_t rowoff = ((size_t)bh * S2 + r0 + 32 * w + 16 * s + quad * 4 + reg) * DHEAD;
            #pragma unroll
            for (int nt = 0; nt < 4; ++nt)
                Ob[rowoff + nt * 16 + l15] = f2bf(oacc[s][nt][reg] * inv);
        }
}

// ---------------------------------------------------------------------------
// Proj MFMA GEMM: out[4096,1024] (f32) = gather(O)[4096,1024] @ Wob^T + b_out.
// Re-tiled BM=128 x BN=64 -> grid (16,32) = 512 blocks = 2/CU (was 1/CU).
// Waves 2x2, each 64x32 (acc 4x2 frags). Epilogue: LDS transpose -> f32x4.
// ---------------------------------------------------------------------------
__global__ __launch_bounds__(256) void proj_gemm_mfma(
    const ushort_t* __restrict__ Ob, const ushort_t* __restrict__ Wob,
    const float* __restrict__ Bo, float* __restrict__ Out)
{
    __shared__ ushort_t As[128 * 32];
    __shared__ ushort_t Bs[64 * 32];
    __shared__ float    Sc[4][16 * 20];
    const int t = threadIdx.x;
    const int lane = t & 63, quad = lane >> 4, l15 = lane & 15;
    const int w = t >> 6;
    const int wm = (w >> 1) * 64, wn = (w & 1) * 32;
    const int r0 = blockIdx.y * 128, c0 = blockIdx.x * 64;
    const int branch = r0 >> 11, bb = (r0 & 2047) >> 10;

    const int g_chunk = (lane & 3) ^ ((lane >> 3) & 3);
    const int srow_lo = w * 16 + (lane >> 2);

    f32x4 acc[4][2];
    #pragma unroll
    for (int i = 0; i < 4; ++i)
        #pragma unroll
        for (int j = 0; j < 2; ++j) acc[i][j] = (f32x4){0.f, 0.f, 0.f, 0.f};

    for (int k0 = 0; k0 < HDIM; k0 += 32) {
        int h = k0 >> 6, off = k0 & 63;
        __syncthreads();
        {   // B: 64 rows, one issue per wave
            const ushort_t* gpB = Wob + (size_t)(c0 + srow_lo) * HDIM + k0 + g_chunk * 8;
            ushort_t* lpB = Bs + w * 512;
            __builtin_amdgcn_global_load_lds(
                (const __attribute__((address_space(1))) void*)gpB,
                (__attribute__((address_space(3))) void*)lpB, 16, 0, 0);
        }
        #pragma unroll
        for (int p = 0; p < 2; ++p) {   // A: 128 rows, two issues per wave
            int row = srow_lo + p * 64;
            int s = branch * NSEQ + (r0 & 1023) + row;
            const ushort_t* gpA = Ob + ((size_t)(bb * NHEADS + h) * S2 + s) * DHEAD + off + g_chunk * 8;
            ushort_t* lpA = As + p * 2048 + w * 512;
            __builtin_amdgcn_global_load_lds(
                (const __attribute__((address_space(1))) void*)gpA,
                (__attribute__((address_space(3))) void*)lpA, 16, 0, 0);
        }
        __syncthreads();
        const int sw = (l15 >> 1) & 3;
        short8 af[4], bf[2];
        #pragma unroll
        for (int mi = 0; mi < 4; ++mi) {
            int ra = wm + mi * 16 + l15;
            af[mi] = *(const short8*)(As + ra * 32 + ((quad ^ sw) * 8));
        }
        #pragma unroll
        for (int ni = 0; ni < 2; ++ni) {
            int rb = wn + ni * 16 + l15;
            bf[ni] = *(const short8*)(Bs + rb * 32 + ((quad ^ sw) * 8));
        }
        #pragma unroll
        for (int mi = 0; mi < 4; ++mi)
            #pragma unroll
            for (int ni = 0; ni < 2; ++ni)
                acc[mi][ni] = __builtin_amdgcn_mfma_f32_16x16x32_bf16(af[mi], bf[ni], acc[mi][ni], 0, 0, 0);
    }

    float* sc = &Sc[w][0];
    const int row = lane >> 2, ch = lane & 3;
    #pragma unroll
    for (int mi = 0; mi < 4; ++mi) {
        int rb0 = r0 + wm + mi * 16;
        #pragma unroll
        for (int ni = 0; ni < 2; ++ni) {
            int cb = c0 + wn + ni * 16;
            #pragma unroll
            for (int reg = 0; reg < 4; ++reg)
                sc[(quad * 4 + reg) * 20 + l15] = acc[mi][ni][reg];
            float4 v = *(const float4*)&sc[row * 20 + ch * 4];
            float4 bias = *(const float4*)&Bo[cb + ch * 4];
            v.x += bias.x; v.y += bias.y; v.z += bias.z; v.w += bias.w;
            *(float4*)&Out[(size_t)(rb0 + row) * HDIM + cb + ch * 4] = v;
        }
    }
}

extern "C" void kernel_launch(void* const* d_in, const int* in_sizes, int n_in,
                              void* d_out, int out_size, void* d_ws, size_t ws_size,
                              hipStream_t stream) {
    const float* x    = (const float*)d_in[0];
    const float* x2   = (const float*)d_in[1];
    const float* wqkv = (const float*)d_in[2];
    const float* wout = (const float*)d_in[3];
    const float* bout = (const float*)d_in[4];
    float* out = (float*)d_out;

    // ws layout (bytes): Xb 8M | Wqb 6M | Wob 2M | Qb 8M | Kb 8M | Vtb 8M | Ob 8M = 48 MB
    char* ws = (char*)d_ws;
    ushort_t* Xb  = (ushort_t*)(ws);
    ushort_t* Wqb = (ushort_t*)(ws + (8u  << 20));
    ushort_t* Wob = (ushort_t*)(ws + (14u << 20));
    ushort_t* Qb  = (ushort_t*)(ws + (16u << 20));
    ushort_t* Kb  = (ushort_t*)(ws + (24u << 20));
    ushort_t* Vtb = (ushort_t*)(ws + (32u << 20));
    ushort_t* Ob  = (ushort_t*)(ws + (40u << 20));

    cvt_all<<<8192, 256, 0, stream>>>(x, x2, wqkv, wout, Xb, Wqb, Wob);
    qkv_gemm_mfma<<<dim3(24, 32), 256, 0, stream>>>(Xb, Wqb, Qb, Kb, Vtb);
    attn_mfma<<<dim3(S2 / 128, NHEADS, NB), 256, 0, stream>>>(Qb, Kb, Vtb, Ob);
    proj_gemm_mfma<<<dim3(16, 32), 256, 0, stream>>>(Ob, Wob, bout, out);
}

// Round 10
// 212.483 us; speedup vs baseline: 1.0815x; 1.0571x over previous
//
#include <hip/hip_runtime.h>
#include <hip/hip_bf16.h>

// B=2, N=1024/branch, H=1024, NH=16, d=64, S=2N=2048. I/O f32; compute bf16 MFMA.
#define NB      2
#define NSEQ    1024
#define S2      2048
#define HDIM    1024
#define NHEADS  16
#define DHEAD   64
// Q is pre-scaled by 0.125*log2(e) in the QKV epilogue; attention uses exp2.
#define Q_SCALE 0.18033688011112042f

typedef unsigned short ushort_t;
typedef __attribute__((ext_vector_type(8))) short short8;   // 8 bf16 = 4 VGPR (MFMA A/B frag)
typedef __attribute__((ext_vector_type(4))) float f32x4;    // MFMA C/D frag

__device__ __forceinline__ ushort_t f2bf(float f) {
    union { float f; unsigned int u; } c; c.f = f;
    unsigned int u = c.u;
    u += 0x7FFFu + ((u >> 16) & 1u);   // RTNE
    return (ushort_t)(u >> 16);
}

__device__ __forceinline__ unsigned pack_bf16x2(float a, float b) {
    union { __hip_bfloat162 h; unsigned u; } cv;
    cv.h = __float22bfloat162_rn(float2{a, b});   // v_cvt_pk_bf16_f32 on gfx950
    return cv.u;
}

// ---------------------------------------------------------------------------
// One-shot f32 -> bf16 convert of x, x2, w_qkv, w_out into workspace.
// ---------------------------------------------------------------------------
__global__ __launch_bounds__(256) void cvt_all(
    const float* __restrict__ x, const float* __restrict__ x2,
    const float* __restrict__ wqkv, const float* __restrict__ wout,
    ushort_t* __restrict__ Xb, ushort_t* __restrict__ Wqb, ushort_t* __restrict__ Wob)
{
    int b = blockIdx.x;
    const float* s; ushort_t* d; int i;
    if (b < 2048)      { s = x;    d = Xb;            i = b * 256 + threadIdx.x; }
    else if (b < 4096) { s = x2;   d = Xb + 2097152;  i = (b - 2048) * 256 + threadIdx.x; }
    else if (b < 7168) { s = wqkv; d = Wqb;           i = (b - 4096) * 256 + threadIdx.x; }
    else               { s = wout; d = Wob;           i = (b - 7168) * 256 + threadIdx.x; }
    float4 v = ((const float4*)s)[i];
    ushort4 o; o.x = f2bf(v.x); o.y = f2bf(v.y); o.z = f2bf(v.z); o.w = f2bf(v.w);
    ((ushort4*)d)[i] = o;
}

// ---------------------------------------------------------------------------
// QKV MFMA GEMM: C[4096,3072] = Xb @ Wqb^T. 128x128 tile, BK=32, async
// global_load_lds DOUBLE-BUFFERED (one barrier per K-iter, prefetch issued
// after the barrier -> vmcnt drain free). Epilogue: Q (scaled), K -> [b,h,s,d]
// via per-wave LDS transpose -> packed 8B stores; V -> [b,h,d,s] ushort4.
// ---------------------------------------------------------------------------
__global__ __launch_bounds__(256) void qkv_gemm_mfma(
    const ushort_t* __restrict__ Xb, const ushort_t* __restrict__ Wqb,
    ushort_t* __restrict__ Qb, ushort_t* __restrict__ Kb, ushort_t* __restrict__ Vtb)
{
    __shared__ ushort_t As[2 * 128 * 32];   // 16 KB (dbuf)
    __shared__ ushort_t Bs[2 * 128 * 32];   // 16 KB
    __shared__ float    Sc[4][16 * 20];     // per-wave epilogue scratch
    const int t = threadIdx.x;
    const int lane = t & 63, quad = lane >> 4, l15 = lane & 15;
    const int w = t >> 6;
    const int wm = (w >> 1) * 64, wn = (w & 1) * 64;
    const int r0 = blockIdx.y * 128, c0 = blockIdx.x * 128;

    const int g_chunk = (lane & 3) ^ ((lane >> 3) & 3);   // lane-const global chunk
    const int srow_lo = w * 16 + (lane >> 2);             // row for issue p=0 (p adds 64)

    auto stage = [&](int k0, int buf) {
        #pragma unroll
        for (int p = 0; p < 2; ++p) {
            int row = srow_lo + p * 64;
            const ushort_t* gpA = Xb  + (size_t)(r0 + row) * HDIM + k0 + g_chunk * 8;
            const ushort_t* gpB = Wqb + (size_t)(c0 + row) * HDIM + k0 + g_chunk * 8;
            ushort_t* lpA = As + buf * 4096 + p * 2048 + w * 512;
            ushort_t* lpB = Bs + buf * 4096 + p * 2048 + w * 512;
            __builtin_amdgcn_global_load_lds(
                (const __attribute__((address_space(1))) void*)gpA,
                (__attribute__((address_space(3))) void*)lpA, 16, 0, 0);
            __builtin_amdgcn_global_load_lds(
                (const __attribute__((address_space(1))) void*)gpB,
                (__attribute__((address_space(3))) void*)lpB, 16, 0, 0);
        }
    };

    f32x4 acc[4][4];
    #pragma unroll
    for (int i = 0; i < 4; ++i)
        #pragma unroll
        for (int j = 0; j < 4; ++j) acc[i][j] = (f32x4){0.f, 0.f, 0.f, 0.f};

    stage(0, 0);
    stage(32, 1);
    __syncthreads();

    const int sw = (l15 >> 1) & 3;   // (ra>>1)&3 for frag rows
    for (int it = 0; it < 32; ++it) {
        const ushort_t* a = As + (it & 1) * 4096;
        const ushort_t* b = Bs + (it & 1) * 4096;
        short8 af[4], bf[4];
        #pragma unroll
        for (int mi = 0; mi < 4; ++mi) {
            int ra = wm + mi * 16 + l15;
            af[mi] = *(const short8*)(a + ra * 32 + ((quad ^ sw) * 8));
        }
        #pragma unroll
        for (int ni = 0; ni < 4; ++ni) {
            int rb = wn + ni * 16 + l15;
            bf[ni] = *(const short8*)(b + rb * 32 + ((quad ^ sw) * 8));
        }
        #pragma unroll
        for (int mi = 0; mi < 4; ++mi)
            #pragma unroll
            for (int ni = 0; ni < 4; ++ni)
                acc[mi][ni] = __builtin_amdgcn_mfma_f32_16x16x32_bf16(af[mi], bf[ni], acc[mi][ni], 0, 0, 0);
        __syncthreads();   // all waves done with buf (it&1); drain covers prefetch it+1
        if (it < 30) stage((it + 2) * 32, it & 1);
    }

    const int branch = r0 >> 11;
    const int bb     = (r0 & 2047) >> 10;
    const int qi     = c0 >> 10;            // 0=Q 1=K 2=V
    float* sc = &Sc[w][0];

    if (qi == 2) {
        #pragma unroll
        for (int mi = 0; mi < 4; ++mi) {
            int sbase = branch * NSEQ + (r0 & 1023) + wm + mi * 16 + quad * 4;
            #pragma unroll
            for (int ni = 0; ni < 4; ++ni) {
                int cc = (c0 & 1023) + wn + ni * 16;
                int h  = cc >> 6;
                int dd = (cc & 63) + l15;
                ushort4 pv;
                pv.x = f2bf(acc[mi][ni][0]); pv.y = f2bf(acc[mi][ni][1]);
                pv.z = f2bf(acc[mi][ni][2]); pv.w = f2bf(acc[mi][ni][3]);
                *(ushort4*)(Vtb + ((size_t)(bb * NHEADS + h) * DHEAD + dd) * S2 + sbase) = pv;
            }
        }
    } else {
        const float qsc = (qi == 0) ? Q_SCALE : 1.0f;
        ushort_t* base = (qi ? Kb : Qb);
        const int row = lane >> 2, ch = lane & 3;
        #pragma unroll
        for (int mi = 0; mi < 4; ++mi) {
            int sb = branch * NSEQ + (r0 & 1023) + wm + mi * 16;
            #pragma unroll
            for (int ni = 0; ni < 4; ++ni) {
                int cc = (c0 & 1023) + wn + ni * 16;
                int h  = cc >> 6;
                int db = cc & 63;
                #pragma unroll
                for (int reg = 0; reg < 4; ++reg)
                    sc[(quad * 4 + reg) * 20 + l15] = acc[mi][ni][reg] * qsc;
                float4 v = *(const float4*)&sc[row * 20 + ch * 4];
                uint2 pk;
                pk.x = pack_bf16x2(v.x, v.y);
                pk.y = pack_bf16x2(v.z, v.w);
                *(uint2*)(base + ((size_t)(bb * NHEADS + h) * S2 + sb + row) * DHEAD + db + ch * 4) = pk;
            }
        }
    }
}

// ---------------------------------------------------------------------------
// MFMA flash attention v5 per (b,h). Block = 128 q-rows, 4 waves x 32 rows
// (two 16-row sets per wave). K/V async-staged (global_load_lds dbuf,
// 1 barrier/tile, prefetch after barrier). NO-MAX softmax. K/V fragments
// loaded once per tile, reused across both q-sets.
// ---------------------------------------------------------------------------
__global__ __launch_bounds__(256) void attn_mfma(
    const ushort_t* __restrict__ Qb, const ushort_t* __restrict__ Kb,
    const ushort_t* __restrict__ Vtb, ushort_t* __restrict__ Ob)
{
    __shared__ ushort_t Ks[2][64 * 64];
    __shared__ ushort_t Vs[2][64 * 64];
    __shared__ ushort_t Ps[64][72];

    const int t = threadIdx.x, lane = t & 63, quad = lane >> 4, l15 = lane & 15, w = t >> 6;
    const int bh = blockIdx.z * NHEADS + blockIdx.y;
    const int r0 = blockIdx.x * 128;
    const ushort_t* Qh  = Qb  + (size_t)bh * S2 * DHEAD;
    const ushort_t* Kh  = Kb  + (size_t)bh * S2 * DHEAD;
    const ushort_t* Vth = Vtb + (size_t)bh * DHEAD * S2;

    const int slot = lane & 7;
    const int rsub = lane >> 3;
    auto prefetch = [&](int kt_, int buf_) {
        #pragma unroll
        for (int c = 0; c < 2; ++c) {
            int row = w * 16 + c * 8 + rsub;
            int gK  = slot ^ ((row >> 2) & 7);
            int gV  = slot ^ (row & 7);
            const ushort_t* gpK = Kh  + (size_t)(kt_ * 64 + row) * DHEAD + gK * 8;
            const ushort_t* gpV = Vth + (size_t)row * S2 + kt_ * 64 + gV * 8;
            ushort_t* lpK = &Ks[buf_][w * 1024 + c * 512];
            ushort_t* lpV = &Vs[buf_][w * 1024 + c * 512];
            __builtin_amdgcn_global_load_lds(
                (const __attribute__((address_space(1))) void*)gpK,
                (__attribute__((address_space(3))) void*)lpK, 16, 0, 0);
            __builtin_amdgcn_global_load_lds(
                (const __attribute__((address_space(1))) void*)gpV,
                (__attribute__((address_space(3))) void*)lpV, 16, 0, 0);
        }
    };

    short8 aq[2][2];
    #pragma unroll
    for (int s = 0; s < 2; ++s) {
        const int qrow = r0 + 32 * w + 16 * s + l15;
        aq[s][0] = *(const short8*)(Qh + (size_t)qrow * DHEAD + quad * 8);
        aq[s][1] = *(const short8*)(Qh + (size_t)qrow * DHEAD + 32 + quad * 8);
    }

    float lacc[2][4] = {};
    f32x4 oacc[2][4];
    #pragma unroll
    for (int s = 0; s < 2; ++s)
        #pragma unroll
        for (int nt = 0; nt < 4; ++nt) oacc[s][nt] = (f32x4){0.f, 0.f, 0.f, 0.f};

    prefetch(0, 0);
    prefetch(1, 1);
    __syncthreads();

    for (int kt = 0; kt < S2 / 64; ++kt) {
        const ushort_t* kb = &Ks[kt & 1][0];
        const ushort_t* vb = &Vs[kt & 1][0];

        short8 kf[4][2];
        #pragma unroll
        for (int nt = 0; nt < 4; ++nt) {
            const int key = 4 * l15 + nt;
            const ushort_t* krow = kb + key * 64;
            const int swz = l15 & 7;
            kf[nt][0] = *(const short8*)(krow + ((quad       ^ swz) * 8));
            kf[nt][1] = *(const short8*)(krow + (((4 + quad) ^ swz) * 8));
        }

        f32x4 sacc[2][4];
        #pragma unroll
        for (int s = 0; s < 2; ++s)
            #pragma unroll
            for (int nt = 0; nt < 4; ++nt) {
                f32x4 sv = (f32x4){0.f, 0.f, 0.f, 0.f};
                sv = __builtin_amdgcn_mfma_f32_16x16x32_bf16(aq[s][0], kf[nt][0], sv, 0, 0, 0);
                sv = __builtin_amdgcn_mfma_f32_16x16x32_bf16(aq[s][1], kf[nt][1], sv, 0, 0, 0);
                sacc[s][nt] = sv;
            }

        short8 vf[4][2];
        #pragma unroll
        for (int nt = 0; nt < 4; ++nt) {
            const int drow = nt * 16 + l15;
            vf[nt][0] = *(const short8*)(vb + drow * 64 + ((quad       ^ (drow & 7)) * 8));
            vf[nt][1] = *(const short8*)(vb + drow * 64 + (((4 + quad) ^ (drow & 7)) * 8));
        }

        #pragma unroll
        for (int s = 0; s < 2; ++s) {
            #pragma unroll
            for (int reg = 0; reg < 4; ++reg) {
                float p0 = __builtin_exp2f(sacc[s][0][reg]);
                float p1 = __builtin_exp2f(sacc[s][1][reg]);
                float p2 = __builtin_exp2f(sacc[s][2][reg]);
                float p3 = __builtin_exp2f(sacc[s][3][reg]);
                lacc[s][reg] += (p0 + p1) + (p2 + p3);
                uint2 pk;
                pk.x = pack_bf16x2(p0, p1);
                pk.y = pack_bf16x2(p2, p3);
                int prow = 16 * w + quad * 4 + reg;
                *(uint2*)&Ps[prow][4 * l15] = pk;
            }
            #pragma unroll
            for (int kk = 0; kk < 2; ++kk) {
                short8 pa = *(const short8*)&Ps[16 * w + l15][kk * 32 + quad * 8];
                #pragma unroll
                for (int nt = 0; nt < 4; ++nt)
                    oacc[s][nt] = __builtin_amdgcn_mfma_f32_16x16x32_bf16(pa, vf[nt][kk], oacc[s][nt], 0, 0, 0);
            }
        }

        __syncthreads();
        if (kt + 2 < S2 / 64) prefetch(kt + 2, kt & 1);
    }

    #pragma unroll
    for (int s = 0; s < 2; ++s)
        #pragma unroll
        for (int reg = 0; reg < 4; ++reg) {
            float l = lacc[s][reg];
            l += __shfl_xor(l, 1);
            l += __shfl_xor(l, 2);
            l += __shfl_xor(l, 4);
            l += __shfl_xor(l, 8);
            float inv = 1.f / l;
            size_t rowoff = ((size_t)bh * S2 + r0 + 32 * w + 16 * s + quad * 4 + reg) * DHEAD;
            #pragma unroll
            for (int nt = 0; nt < 4; ++nt)
                Ob[rowoff + nt * 16 + l15] = f2bf(oacc[s][nt][reg] * inv);
        }
}

// ---------------------------------------------------------------------------
// Proj MFMA GEMM: out[4096,1024] (f32) = gather(O)[4096,1024] @ Wob^T + b_out.
// BM=128 x BN=64, grid (16,32)=512 blocks. Async staging double-buffered
// (one barrier per K-iter). Epilogue: LDS transpose -> f32x4 stores.
// ---------------------------------------------------------------------------
__global__ __launch_bounds__(256) void proj_gemm_mfma(
    const ushort_t* __restrict__ Ob, const ushort_t* __restrict__ Wob,
    const float* __restrict__ Bo, float* __restrict__ Out)
{
    __shared__ ushort_t As[2 * 128 * 32];   // 16 KB
    __shared__ ushort_t Bs[2 * 64 * 32];    // 8 KB
    __shared__ float    Sc[4][16 * 20];
    const int t = threadIdx.x;
    const int lane = t & 63, quad = lane >> 4, l15 = lane & 15;
    const int w = t >> 6;
    const int wm = (w >> 1) * 64, wn = (w & 1) * 32;
    const int r0 = blockIdx.y * 128, c0 = blockIdx.x * 64;
    const int branch = r0 >> 11, bb = (r0 & 2047) >> 10;

    const int g_chunk = (lane & 3) ^ ((lane >> 3) & 3);
    const int srow_lo = w * 16 + (lane >> 2);

    auto stage = [&](int k0, int buf) {
        int h = k0 >> 6, off = k0 & 63;
        const ushort_t* gpB = Wob + (size_t)(c0 + srow_lo) * HDIM + k0 + g_chunk * 8;
        ushort_t* lpB = Bs + buf * 2048 + w * 512;
        __builtin_amdgcn_global_load_lds(
            (const __attribute__((address_space(1))) void*)gpB,
            (__attribute__((address_space(3))) void*)lpB, 16, 0, 0);
        #pragma unroll
        for (int p = 0; p < 2; ++p) {
            int row = srow_lo + p * 64;
            int s = branch * NSEQ + (r0 & 1023) + row;
            const ushort_t* gpA = Ob + ((size_t)(bb * NHEADS + h) * S2 + s) * DHEAD + off + g_chunk * 8;
            ushort_t* lpA = As + buf * 4096 + p * 2048 + w * 512;
            __builtin_amdgcn_global_load_lds(
                (const __attribute__((address_space(1))) void*)gpA,
                (__attribute__((address_space(3))) void*)lpA, 16, 0, 0);
        }
    };

    f32x4 acc[4][2];
    #pragma unroll
    for (int i = 0; i < 4; ++i)
        #pragma unroll
        for (int j = 0; j < 2; ++j) acc[i][j] = (f32x4){0.f, 0.f, 0.f, 0.f};

    stage(0, 0);
    stage(32, 1);
    __syncthreads();

    const int sw = (l15 >> 1) & 3;
    for (int it = 0; it < 32; ++it) {
        const ushort_t* a = As + (it & 1) * 4096;
        const ushort_t* b = Bs + (it & 1) * 2048;
        short8 af[4], bf[2];
        #pragma unroll
        for (int mi = 0; mi < 4; ++mi) {
            int ra = wm + mi * 16 + l15;
            af[mi] = *(const short8*)(a + ra * 32 + ((quad ^ sw) * 8));
        }
        #pragma unroll
        for (int ni = 0; ni < 2; ++ni) {
            int rb = wn + ni * 16 + l15;
            bf[ni] = *(const short8*)(b + rb * 32 + ((quad ^ sw) * 8));
        }
        #pragma unroll
        for (int mi = 0; mi < 4; ++mi)
            #pragma unroll
            for (int ni = 0; ni < 2; ++ni)
                acc[mi][ni] = __builtin_amdgcn_mfma_f32_16x16x32_bf16(af[mi], bf[ni], acc[mi][ni], 0, 0, 0);
        __syncthreads();
        if (it < 30) stage((it + 2) * 32, it & 1);
    }

    float* sc = &Sc[w][0];
    const int row = lane >> 2, ch = lane & 3;
    #pragma unroll
    for (int mi = 0; mi < 4; ++mi) {
        int rb0 = r0 + wm + mi * 16;
        #pragma unroll
        for (int ni = 0; ni < 2; ++ni) {
            int cb = c0 + wn + ni * 16;
            #pragma unroll
            for (int reg = 0; reg < 4; ++reg)
                sc[(quad * 4 + reg) * 20 + l15] = acc[mi][ni][reg];
            float4 v = *(const float4*)&sc[row * 20 + ch * 4];
            float4 bias = *(const float4*)&Bo[cb + ch * 4];
            v.x += bias.x; v.y += bias.y; v.z += bias.z; v.w += bias.w;
            *(float4*)&Out[(size_t)(rb0 + row) * HDIM + cb + ch * 4] = v;
        }
    }
}

extern "C" void kernel_launch(void* const* d_in, const int* in_sizes, int n_in,
                              void* d_out, int out_size, void* d_ws, size_t ws_size,
                              hipStream_t stream) {
    const float* x    = (const float*)d_in[0];
    const float* x2   = (const float*)d_in[1];
    const float* wqkv = (const float*)d_in[2];
    const float* wout = (const float*)d_in[3];
    const float* bout = (const float*)d_in[4];
    float* out = (float*)d_out;

    // ws layout (bytes): Xb 8M | Wqb 6M | Wob 2M | Qb 8M | Kb 8M | Vtb 8M | Ob 8M = 48 MB
    char* ws = (char*)d_ws;
    ushort_t* Xb  = (ushort_t*)(ws);
    ushort_t* Wqb = (ushort_t*)(ws + (8u  << 20));
    ushort_t* Wob = (ushort_t*)(ws + (14u << 20));
    ushort_t* Qb  = (ushort_t*)(ws + (16u << 20));
    ushort_t* Kb  = (ushort_t*)(ws + (24u << 20));
    ushort_t* Vtb = (ushort_t*)(ws + (32u << 20));
    ushort_t* Ob  = (ushort_t*)(ws + (40u << 20));

    cvt_all<<<8192, 256, 0, stream>>>(x, x2, wqkv, wout, Xb, Wqb, Wob);
    qkv_gemm_mfma<<<dim3(24, 32), 256, 0, stream>>>(Xb, Wqb, Qb, Kb, Vtb);
    attn_mfma<<<dim3(S2 / 128, NHEADS, NB), 256, 0, stream>>>(Qb, Kb, Vtb, Ob);
    proj_gemm_mfma<<<dim3(16, 32), 256, 0, stream>>>(Ob, Wob, bout, out);
}